// Round 18
// baseline (47.399 us; speedup 1.0000x reference)
//
#include <hip/hip_runtime.h>

#define TPB   64     // one wave per block; fully wave-private, zero s_barrier
#define RPS   64     // rows per slab (one per lane)
#define XDIM  99
#define NJ    26
#define OUTW  78
#define SLABF (RPS * XDIM)   // 6336 floats = 25344 B

__device__ __forceinline__ float fast_rcp(float a)  { return __builtin_amdgcn_rcpf(a); }
__device__ __forceinline__ float fast_sqrt(float a) { return __builtin_amdgcn_sqrtf(a); }

__device__ __forceinline__ void rodrigues(float ax, float ay, float az, float* R) {
    const float EPS = 1.1920928955078125e-07f;   // np.finfo(np.float32).eps
    float t = fast_sqrt(ax*ax + ay*ay + az*az);
    float inv = fast_rcp(t + EPS);
    float r0 = ax*inv, r1 = ay*inv, r2 = az*inv;
    float s, c;
    __sincosf(t, &s, &c);
    float omc = 1.0f - c;
    float r00 = r0*r0, r11 = r1*r1, r22 = r2*r2;
    float r01 = r0*r1, r02 = r0*r2, r12 = r1*r2;
    R[0] = 1.0f - omc*(r11 + r22);
    R[1] = -s*r2 + omc*r01;
    R[2] =  s*r1 + omc*r02;
    R[3] =  s*r2 + omc*r01;
    R[4] = 1.0f - omc*(r00 + r22);
    R[5] = -s*r0 + omc*r12;
    R[6] = -s*r1 + omc*r02;
    R[7] =  s*r0 + omc*r12;
    R[8] = 1.0f - omc*(r00 + r11);
}

// Issue one slab's DMA: 24 x 16B-wide + 3 x 4B-wide = 27 vm-ops (R17-proven).
__device__ __forceinline__ void dma_slab(const float* gsrc, float* lbuf, int l) {
    #pragma unroll
    for (int j = 0; j < 24; ++j) {
        __builtin_amdgcn_global_load_lds(
            (const __attribute__((address_space(1))) unsigned int*)(gsrc + 256*j + 4*l),
            (__attribute__((address_space(3))) unsigned int*)(lbuf + 256*j),
            16, 0, 0);
    }
    #pragma unroll
    for (int kk = 0; kk < 3; ++kk) {
        __builtin_amdgcn_global_load_lds(
            (const __attribute__((address_space(1))) unsigned int*)(gsrc + 6144 + 64*kk + l),
            (__attribute__((address_space(3))) unsigned int*)(lbuf + 6144 + 64*kk),
            4, 0, 0);
    }
}

// Compute 64 rows (row-per-lane), pack pos in place, flush linearly.
__device__ __forceinline__ void process_slab(float* slab, float* ob, 
                                             const float* __restrict__ off, int l) {
    constexpr int OFF_IDX[NJ] = {0,1,2,3,4,6,7,8,9,11,12,13,14,15,16,17,18,19,20,22,24,25,26,27,28,30};
    constexpr int PAR[NJ]     = {-1,0,1,2,3,0,5,6,7,0,9,10,11,12,10,14,15,16,17,17,10,20,21,22,23,23};

    const float* row = &slab[l * XDIM];          // stride 99 -> conflict-free
    float ang[NJ][9];                            // compile-time idx -> registers
    float pp[NJ][3];

    {
        float R[9];
        rodrigues(row[3], row[4], row[5], R);
        #pragma unroll
        for (int q = 0; q < 9; ++q) ang[0][q] = R[q];
        pp[0][0] = off[0] + row[0];
        pp[0][1] = off[1] + row[1];
        pp[0][2] = off[2] + row[2];
    }
    #pragma unroll
    for (int s = 1; s < NJ; ++s) {
        const int i  = OFF_IDX[s];
        const int pa = PAR[s];
        float L[9];
        rodrigues(row[3*i+3], row[3*i+4], row[3*i+5], L);
        const float o0 = off[3*i], o1 = off[3*i+1], o2 = off[3*i+2];  // uniform
        #pragma unroll
        for (int c = 0; c < 3; ++c)
            pp[s][c] = o0*ang[pa][c] + o1*ang[pa][3+c] + o2*ang[pa][6+c] + pp[pa][c];
        #pragma unroll
        for (int j = 0; j < 3; ++j)
            #pragma unroll
            for (int kk = 0; kk < 3; ++kk)
                ang[s][3*j+kk] = L[3*j+0]*ang[pa][0+kk]
                               + L[3*j+1]*ang[pa][3+kk]
                               + L[3*j+2]*ang[pa][6+kk];
    }

    // compiler fence: all compute ds_reads stay before pack ds_writes
    // (lockstep wave => all lanes' reads done at this PC; in-order per-wave LDS issue)
    asm volatile("" ::: "memory");

    // ---- pack pos into dead slab at stride 78 (float2, 8B-aligned) ----
    {
        float2* wr2 = reinterpret_cast<float2*>(slab) + 39 * l;
        #pragma unroll
        for (int j = 0; j < 39; ++j) {
            float2 v;
            v.x = pp[(2*j)   / 3][(2*j)   % 3];
            v.y = pp[(2*j+1) / 3][(2*j+1) % 3];
            wr2[j] = v;
        }
    }
    asm volatile("s_waitcnt lgkmcnt(0)" ::: "memory");   // pack visible to flush reads

    // ---- flush: pure linear copy, full 64B lines, single touch.
    //      19 x dwordx4 + 1 x dwordx2 stores per lane = 20 vm-ops. ----
    {
        float4* ob4 = reinterpret_cast<float4*>(ob);
        const float4* b4 = reinterpret_cast<const float4*>(slab);
        #pragma unroll
        for (int j = 0; j < 19; ++j)
            ob4[l + 64*j] = b4[l + 64*j];
        float2* ob2 = reinterpret_cast<float2*>(ob);
        const float2* b2 = reinterpret_cast<const float2*>(slab);
        ob2[2432 + l] = b2[2432 + l];
    }
}

// (64,4): VGPR cap 128 (R17 measured 92). LDS 50688B -> 3 blocks/CU; the win
// is per-wave memory/compute overlap, not residency.
__global__ __launch_bounds__(TPB, 4) void skel_fk(const float* __restrict__ x,
                                                  const float* __restrict__ off,
                                                  float* __restrict__ out) {
    __shared__ __align__(16) float buf[2][SLABF];     // 2 x 25344 B
    const int l = threadIdx.x;
    const int row0 = blockIdx.x * (2 * RPS);          // 128 rows per block
    const float* g0 = x + (long long)row0 * XDIM;
    const float* g1 = g0 + SLABF;
    float* o0 = out + (long long)row0 * OUTW;
    float* o1 = o0 + RPS * OUTW;

    // ---- issue BOTH slabs' DMA up front: 54 vm-ops in flight ----
    dma_slab(g0, buf[0], l);
    dma_slab(g1, buf[1], l);

    // wait slab0 only: 27 newer ops (slab1) may remain outstanding
    asm volatile("s_waitcnt vmcnt(27)" ::: "memory");
    process_slab(buf[0], o0, off, l);            // slab1 lands under this compute

    // wait all 54 loads: vm ops retire in issue order, so <=12 outstanding
    // (flush0's 20 stores are the newest) => every load retired. 12 < 20 gives
    // margin if the compiler emits fewer store instructions than expected.
    asm volatile("s_waitcnt vmcnt(12)" ::: "memory");
    process_slab(buf[1], o1, off, l);            // flush0 stores drain under this
}

extern "C" void kernel_launch(void* const* d_in, const int* in_sizes, int n_in,
                              void* d_out, int out_size, void* d_ws, size_t ws_size,
                              hipStream_t stream) {
    const float* x   = (const float*)d_in[0];
    const float* off = (const float*)d_in[1];
    float* out = (float*)d_out;
    const int B = in_sizes[0] / XDIM;      // 262144
    const int grid = B / (2 * RPS);        // 2048
    skel_fk<<<grid, TPB, 0, stream>>>(x, off, out);
}